// Round 1
// baseline (707.228 us; speedup 1.0000x reference)
//
#include <hip/hip_runtime.h>
#include <hip/hip_bf16.h>

typedef __bf16 bf16x8 __attribute__((ext_vector_type(8)));
typedef float f32x4 __attribute__((ext_vector_type(4)));

#define NTOT   131072
#define NODES_PER_AUDIO 2048
#define NAUDIO 64
#define POOL_CHUNKS 16
#define CHUNK_NODES (NODES_PER_AUDIO / POOL_CHUNKS)   // 128

// ---------------------------------------------------------------------------
// dtype detection: bits 7..14 of each 32-bit word. bf16 pairs -> low elem's
// exponent concentrated near 127; f32 -> uniform mantissa bits (~18% hit).
// flag = 1 -> bf16 inputs ; flag = 0 -> f32 inputs
// ---------------------------------------------------------------------------
__global__ __launch_bounds__(256)
void detect_dtype(const unsigned* __restrict__ x, int* __restrict__ flag)
{
    const int tid = threadIdx.x;
    int cnt = 0;
    for (int i = tid; i < 4096; i += 256) {
        unsigned e = (x[i] >> 7) & 0xFF;
        cnt += (e >= 100 && e <= 145) ? 1 : 0;
    }
    __shared__ int red[256];
    red[tid] = cnt; __syncthreads();
    for (int s = 128; s > 0; s >>= 1) {
        if (tid < s) red[tid] += red[tid + s];
        __syncthreads();
    }
    if (tid == 0) *flag = (red[0] > 3000) ? 1 : 0;
}

struct W14 { const void* s[14]; int n[14]; int off[14]; };

__global__ __launch_bounds__(256)
void convert_weights(W14 w, const int* __restrict__ flag, __bf16* __restrict__ wb)
{
    const int f = *flag;
    const int stride = gridDim.x * 256;
    for (int t = 0; t < 14; t++) {
        const void* src = w.s[t];
        __bf16* d = wb + w.off[t];
        for (int i = blockIdx.x * 256 + threadIdx.x; i < w.n[t]; i += stride)
            d[i] = f ? ((const __bf16*)src)[i] : (__bf16)((const float*)src)[i];
    }
}

// f32 -> bf16 conversion of x (only runs when flag==0; no-op for bf16 input)
__global__ __launch_bounds__(256)
void convert_x(const float4* __restrict__ xf, __bf16* __restrict__ xb,
               const int* __restrict__ flag)
{
    if (*flag) return;
    const unsigned stride = gridDim.x * 256;
    for (unsigned i = blockIdx.x * 256 + threadIdx.x; i < 16777216u; i += stride) {
        float4 v = xf[i];
        __bf16 t[4] = {(__bf16)v.x, (__bf16)v.y, (__bf16)v.z, (__bf16)v.w};
        *(int2*)&xb[(size_t)i * 4] = *(int2*)t;
    }
}

// ---------------------------------------------------------------------------
// 256x256 8-phase GEMM: C[M,Nc] = A[M,K] @ W[Nc,K]^T, bf16 in, bf16 out.
// 512 threads = 8 waves (2M x 4N), per-wave 128x64 output, acc[8][4] f32x4.
// BK=64, 2 K-tiles per iteration, 8 phases/iter, one 16-KB half-tile staged
// per phase via global_load_lds(16B). Counted vmcnt(4) at phases 4/8 only.
// LDS 128 KiB dynamic: As[2][256][64] + Bs[2][256][64].
// T2 swizzle: LDS slot s holds global chunk s^(row&7); read XORs the same.
//   (global_load_lds dest stays linear = base+lane*16; source is pre-swizzled)
// T1: bijective XCD swizzle (nwg%8==0 for both GEMMs).
// T5: setprio(1) around each 16-MFMA cluster.
// Phase->stage map (iter i computes tiles e=2i(buf0), o=2i+1(buf1)):
//  ph1 LDA(e,mh0)+LDB(e,nh0), stage o.A-h0 | ph2 LDB(e,nh1), stage o.A-h1
//  ph3 LDA(e,mh1),            stage (2i+2).B-h0 | ph4 -, stage (2i+2).B-h1, vmcnt(4)
//  ph5..ph8 mirror on buf1 with stages (2i+2).A-h0/h1, (2i+3).B-h0/h1, vmcnt(4)
// Every stage targets a region whose last ds_read completed >=1 barrier before
// the issue; vmcnt(4)+barrier at ph4/ph8 guarantees the next tile has landed
// (queue: 12 outstanding, keep 4 => oldest 8 = the consumed tile's loads done).
// ---------------------------------------------------------------------------
#define SBAR   __builtin_amdgcn_sched_barrier(0)
#define BAR    do { SBAR; __builtin_amdgcn_s_barrier(); SBAR; } while (0)
#define WAITL  do { asm volatile("s_waitcnt lgkmcnt(0)"); SBAR; } while (0)
#define WAITV4 do { asm volatile("s_waitcnt vmcnt(4)"); SBAR; } while (0)

#define STAGE(P, SOFF, LB, BUF, H, KT) do {                                        \
    const __bf16* _g0 = (P) + (SOFF) + (size_t)(H) * 128 * K + (size_t)(KT) * 64;  \
    __bf16* _l0 = (LB) + (BUF) * 16384 + (H) * 8192 + ld0;                         \
    __builtin_amdgcn_global_load_lds(                                              \
        (const __attribute__((address_space(1))) void*)_g0,                        \
        (__attribute__((address_space(3))) void*)_l0, 16, 0, 0);                   \
    __builtin_amdgcn_global_load_lds(                                              \
        (const __attribute__((address_space(1))) void*)(_g0 + (size_t)64 * K),     \
        (__attribute__((address_space(3))) void*)(_l0 + 4096), 16, 0, 0);          \
} while (0)

#define LDA(BUF, MH) do {                                                \
    _Pragma("unroll")                                                    \
    for (int i_ = 0; i_ < 4; i_++) {                                     \
        const int r_ = (wr * 128 + (MH) * 64 + i_ * 16 + lr) * 64;       \
        av[i_][0] = *(const bf16x8*)&As[(BUF) * 16384 + r_ + sw0];       \
        av[i_][1] = *(const bf16x8*)&As[(BUF) * 16384 + r_ + sw1];       \
    } } while (0)

#define LDB(BUF, NH) do {                                                \
    _Pragma("unroll")                                                    \
    for (int j_ = 0; j_ < 2; j_++) {                                     \
        const int r_ = (wc * 64 + (NH) * 32 + j_ * 16 + lr) * 64;        \
        bv[(NH)][j_][0] = *(const bf16x8*)&Bs[(BUF) * 16384 + r_ + sw0]; \
        bv[(NH)][j_][1] = *(const bf16x8*)&Bs[(BUF) * 16384 + r_ + sw1]; \
    } } while (0)

#define MM(MH, NH) do {                                                       \
    __builtin_amdgcn_s_setprio(1);                                            \
    _Pragma("unroll")                                                         \
    for (int i_ = 0; i_ < 4; i_++)                                            \
    _Pragma("unroll")                                                         \
    for (int j_ = 0; j_ < 2; j_++) {                                          \
        acc[(MH)*4+i_][(NH)*2+j_] = __builtin_amdgcn_mfma_f32_16x16x32_bf16(  \
            av[i_][0], bv[(NH)][j_][0], acc[(MH)*4+i_][(NH)*2+j_], 0, 0, 0);  \
        acc[(MH)*4+i_][(NH)*2+j_] = __builtin_amdgcn_mfma_f32_16x16x32_bf16(  \
            av[i_][1], bv[(NH)][j_][1], acc[(MH)*4+i_][(NH)*2+j_], 0, 0, 0);  \
    }                                                                         \
    __builtin_amdgcn_s_setprio(0); } while (0)

template<bool DYN>
__global__ __launch_bounds__(512, 2)
void gemm8p(const void* __restrict__ Araw, const __bf16* __restrict__ Aconv,
            const __bf16* __restrict__ W, __bf16* __restrict__ C,
            int M, int K, int Nc, int NXC, const int* __restrict__ flagp)
{
    extern __shared__ __align__(16) char smem[];
    __bf16* As = (__bf16*)smem;            // [2][256][64]
    __bf16* Bs = As + 2 * 256 * 64;        // [2][256][64]

    const __bf16* A = (const __bf16*)Araw;
    if constexpr (DYN) { if (!*flagp) A = Aconv; }

    // bijective XCD swizzle (gridDim.x % 8 == 0): each XCD gets a contiguous
    // stripe; column tiles of one row adjacent in time -> A row crosses HBM once
    const int cpx = gridDim.x >> 3;
    const int bid = blockIdx.x;
    const int gid = (bid & 7) * cpx + (bid >> 3);
    const int by = gid / NXC, bx = gid % NXC;
    const int rowBase = by * 256, colBase = bx * 256;

    const int tid = threadIdx.x;
    const int wave = tid >> 6, lane = tid & 63;
    const int lr = lane & 15, lq = lane >> 4;
    const int wr = wave >> 2, wc = wave & 3;
    // swizzled read chunk offsets (elements): chunk q=kk*4+lq, slot q^(row&7)
    const int sw0 = ((lq ^ (lr & 7)) * 8);
    const int sw1 = (((4 + lq) ^ (lr & 7)) * 8);

    // staging: thread owns chunks tid and tid+512 of each 1024-chunk half-tile.
    // chunk c: LDS row c>>3, slot c&7 -> fetch global chunk (c&7)^(row&7).
    // LDS dest = wave*1024B + lane*16B (linear in lane, as gll requires);
    // chunk tid+512 adds uniform +64 rows (row&7 unchanged -> same q).
    const int crow = tid >> 3, cs = tid & 7;
    const int cq = cs ^ (crow & 7);
    const size_t soA = (size_t)(rowBase + crow) * K + cq * 8;
    const size_t soB = (size_t)(colBase + crow) * K + cq * 8;
    const int ld0 = crow * 64 + cs * 8;

    const int NT = K >> 6;

    f32x4 acc[8][4] = {};
    bf16x8 av[4][2], bv[2][2][2];

    // prologue: T0 fully + T1.B, then ensure T0 landed (drop to 4 outstanding)
    STAGE(A, soA, As, 0, 0, 0); STAGE(A, soA, As, 0, 1, 0);
    STAGE(W, soB, Bs, 0, 0, 0); STAGE(W, soB, Bs, 0, 1, 0);
    STAGE(W, soB, Bs, 1, 0, 1); STAGE(W, soB, Bs, 1, 1, 1);
    WAITV4; BAR;

    const int NIT = K >> 7;
    for (int it = 0; it < NIT; ++it) {
        const int t1 = 2 * it + 1;
        const int t2 = (2 * it + 2 < NT) ? 2 * it + 2 : NT - 1;  // clamp: last
        const int t3 = (2 * it + 3 < NT) ? 2 * it + 3 : NT - 1;  // iter garbage
        // ---- K-tile e = 2it (buf0) ----
        LDA(0, 0); LDB(0, 0);
        STAGE(A, soA, As, 1, 0, t1);
        BAR; WAITL; MM(0, 0); BAR;

        LDB(0, 1);
        STAGE(A, soA, As, 1, 1, t1);
        BAR; WAITL; MM(0, 1); BAR;

        LDA(0, 1);
        STAGE(W, soB, Bs, 0, 0, t2);
        BAR; WAITL; MM(1, 1); BAR;

        STAGE(W, soB, Bs, 0, 1, t2);
        BAR; MM(1, 0); WAITV4; BAR;
        // ---- K-tile o = 2it+1 (buf1) ----
        LDA(1, 0); LDB(1, 0);
        STAGE(A, soA, As, 0, 0, t2);
        BAR; WAITL; MM(0, 0); BAR;

        LDB(1, 1);
        STAGE(A, soA, As, 0, 1, t2);
        BAR; WAITL; MM(0, 1); BAR;

        LDA(1, 1);
        STAGE(W, soB, Bs, 1, 0, t3);
        BAR; WAITL; MM(1, 1); BAR;

        STAGE(W, soB, Bs, 1, 1, t3);
        BAR; MM(1, 0); WAITV4; BAR;
    }

    // epilogue: C/D layout col=lane&15, row=(lane>>4)*4+r (proven mapping)
    #pragma unroll
    for (int mh = 0; mh < 2; mh++)
    #pragma unroll
    for (int i = 0; i < 4; i++)
    #pragma unroll
    for (int nh = 0; nh < 2; nh++)
    #pragma unroll
    for (int j = 0; j < 2; j++) {
        const int col = colBase + wc * 64 + nh * 32 + j * 16 + lr;
        #pragma unroll
        for (int r = 0; r < 4; r++) {
            const int row = rowBase + wr * 128 + mh * 64 + i * 16 + lq * 4 + r;
            C[(size_t)row * Nc + col] = (__bf16)acc[mh * 4 + i][nh * 2 + j][r];
        }
    }
}

// ---------------------------------------------------------------------------
// Fused GAT edge-softmax + aggregation (+ optional node head).
// One wave per node n. In-edges = {self, n-1 if same audio}.
// ---------------------------------------------------------------------------
template<int C, bool RELU, bool FUSE_HEAD>
__global__ __launch_bounds__(256)
void agg_fused(const __bf16* __restrict__ h, const __bf16* __restrict__ a_s,
               const __bf16* __restrict__ a_d, const __bf16* __restrict__ bias,
               void* __restrict__ outv,
               const __bf16* __restrict__ Wn, const __bf16* __restrict__ bn,
               const __bf16* __restrict__ Wt, const __bf16* __restrict__ bt,
               void* __restrict__ node_pred, float* __restrict__ logit,
               const int* __restrict__ flag)
{
    constexpr int D = 2 * C;
    constexpr int V = D / 64;
    const int n = blockIdx.x * 4 + (threadIdx.x >> 6);
    const int lane = threadIdx.x & 63;
    const bool have_prev = (n & (NODES_PER_AUDIO - 1)) != 0;
    const size_t np = have_prev ? (size_t)(n - 1) : (size_t)n;
    const int base = lane * V;

    __bf16 h0v[V], h1v[V];
    if constexpr (V == 8) {
        *(int4*)h0v = *(const int4*)(h + (size_t)n * D + base);
        *(int4*)h1v = *(const int4*)(h + np * D + base);
    } else {
        *(int2*)h0v = *(const int2*)(h + (size_t)n * D + base);
        *(int2*)h1v = *(const int2*)(h + np * D + base);
    }

    float ps = 0.f, pd = 0.f, pp = 0.f;
    #pragma unroll
    for (int j = 0; j < V; j++) {
        float av = (float)a_s[base + j], dv = (float)a_d[base + j];
        float x0 = (float)h0v[j], x1 = (float)h1v[j];
        ps += x0 * av; pd += x0 * dv; pp += x1 * av;
    }
    #pragma unroll
    for (int off = 1; off < 32; off <<= 1) {
        ps += __shfl_xor(ps, off, 64);
        pd += __shfl_xor(pd, off, 64);
        pp += __shfl_xor(pp, off, 64);
    }

    float es = ps + pd;  es = es > 0.f ? es : 0.2f * es;
    float a_self = 1.f, a_prev = 0.f;
    if (have_prev) {
        float ep = pp + pd;  ep = ep > 0.f ? ep : 0.2f * ep;
        float m = fmaxf(es, ep);
        float wsx = __expf(es - m), wpx = __expf(ep - m);
        float inv = 1.f / (wsx + wpx);
        a_self = wsx * inv; a_prev = wpx * inv;
    }

    const int cb = (lane & 31) * V;
    float outj[V];
    #pragma unroll
    for (int j = 0; j < V; j++) {
        float p = a_self * (float)h0v[j] + a_prev * (float)h1v[j];
        p = 0.5f * (p + __shfl_xor(p, 32, 64));
        p += (float)bias[cb + j];
        if (RELU) p = fmaxf(p, 0.f);
        outj[j] = p;
    }

    if constexpr (!FUSE_HEAD) {
        if (lane < 32) {
            __bf16 ov[V];
            #pragma unroll
            for (int j = 0; j < V; j++) ov[j] = (__bf16)outj[j];
            if constexpr (V == 8)
                *(int4*)((__bf16*)outv + (size_t)n * C + cb) = *(int4*)ov;
            else
                *(int2*)((__bf16*)outv + (size_t)n * C + cb) = *(int2*)ov;
        }
    } else {
        if (lane < 32)
            *(float4*)((float*)outv + (size_t)n * C + cb) = *(float4*)outj;

        float acc[8];
        #pragma unroll
        for (int k = 0; k < 7; k++) {
            float a = 0.f;
            #pragma unroll
            for (int j = 0; j < V; j++)
                a += outj[j] * (float)Wn[k * C + cb + j];
            acc[k] = a;
        }
        {
            float a = 0.f;
            #pragma unroll
            for (int j = 0; j < V; j++)
                a += outj[j] * (float)Wt[cb + j];
            acc[7] = a;
        }
        #pragma unroll
        for (int off = 1; off < 32; off <<= 1)
            #pragma unroll
            for (int k = 0; k < 8; k++)
                acc[k] += __shfl_xor(acc[k], off, 64);

        if (lane == 0) {
            float lg[7], m = -1e30f;
            #pragma unroll
            for (int k = 0; k < 7; k++) {
                lg[k] = acc[k] + (float)bn[k];
                m = fmaxf(m, lg[k]);
            }
            float s = 0.f;
            #pragma unroll
            for (int k = 0; k < 7; k++) { lg[k] = __expf(lg[k] - m); s += lg[k]; }
            float inv = 1.f / s;
            if (*flag) {
                #pragma unroll
                for (int k = 0; k < 7; k++)
                    ((__bf16*)node_pred)[(size_t)n * 7 + k] = (__bf16)(lg[k] * inv);
            } else {
                #pragma unroll
                for (int k = 0; k < 7; k++)
                    ((float*)node_pred)[(size_t)n * 7 + k] = lg[k] * inv;
            }
            logit[n] = acc[7] + (float)bt[0];
        }
    }
}

// ---------------------------------------------------------------------------
__global__ __launch_bounds__(256)
void audio_stats(const float* __restrict__ logit, float2* __restrict__ stats)
{
    const int b = blockIdx.x;
    const int tid = threadIdx.x;
    __shared__ float red[256];
    const float* lg = logit + b * NODES_PER_AUDIO;

    float m = -1e30f;
    for (int i = tid; i < NODES_PER_AUDIO; i += 256) m = fmaxf(m, lg[i]);
    red[tid] = m; __syncthreads();
    for (int s = 128; s > 0; s >>= 1) {
        if (tid < s) red[tid] = fmaxf(red[tid], red[tid + s]);
        __syncthreads();
    }
    m = red[0]; __syncthreads();

    float s = 0.f;
    for (int i = tid; i < NODES_PER_AUDIO; i += 256) s += __expf(lg[i] - m);
    red[tid] = s; __syncthreads();
    for (int st = 128; st > 0; st >>= 1) {
        if (tid < st) red[tid] += red[tid + st];
        __syncthreads();
    }
    if (tid == 0) stats[b] = make_float2(m, 1.f / red[0]);
}

__global__ __launch_bounds__(256)
void audio_partial(const float* __restrict__ emb, const float* __restrict__ logit,
                   const float2* __restrict__ stats, float* __restrict__ partial)
{
    const int b = blockIdx.x >> 4;
    const int chunk = blockIdx.x & 15;
    const int tid = threadIdx.x;
    const int c = tid & 127, half = tid >> 7;
    const float m = stats[b].x, inv = stats[b].y;
    const float* lg = logit + b * NODES_PER_AUDIO;
    const float* eb = emb + (size_t)b * NODES_PER_AUDIO * 128;

    __shared__ float attbuf[256];
    const int n0 = chunk * CHUNK_NODES + half * (CHUNK_NODES / 2);
    float att = 0.f;
    for (int i = n0; i < n0 + CHUNK_NODES / 2; i++) {
        float w = __expf(lg[i] - m) * inv;
        att += w * eb[(size_t)i * 128 + c];
    }
    attbuf[tid] = att; __syncthreads();
    if (tid < 128)
        partial[(size_t)(b * POOL_CHUNKS + chunk) * 128 + tid] =
            attbuf[tid] + attbuf[tid + 128];
}

__global__ __launch_bounds__(64)
void audio_final(const float* __restrict__ partial, const __bf16* __restrict__ Wa,
                 const __bf16* __restrict__ ba, void* __restrict__ outbase,
                 const int* __restrict__ flag)
{
    const int b = blockIdx.x;
    const int lane = threadIdx.x;
    const float* pb = partial + (size_t)b * POOL_CHUNKS * 128;

    float a0 = 0.f, a1 = 0.f;
    #pragma unroll
    for (int k = 0; k < POOL_CHUNKS; k++) {
        a0 += pb[k * 128 + lane * 2];
        a1 += pb[k * 128 + lane * 2 + 1];
    }
    float p0 = a0 * (float)Wa[lane * 2]       + a1 * (float)Wa[lane * 2 + 1];
    float p1 = a0 * (float)Wa[128 + lane * 2] + a1 * (float)Wa[128 + lane * 2 + 1];
    #pragma unroll
    for (int off = 1; off < 64; off <<= 1) {
        p0 += __shfl_xor(p0, off, 64);
        p1 += __shfl_xor(p1, off, 64);
    }
    if (lane == 0) {
        float r0 = p0 + (float)ba[0];
        float r1 = p1 + (float)ba[1];
        if (*flag) {
            ((__bf16*)outbase)[(size_t)NTOT * 7 + b * 2 + 0] = (__bf16)r0;
            ((__bf16*)outbase)[(size_t)NTOT * 7 + b * 2 + 1] = (__bf16)r1;
        } else {
            ((float*)outbase)[(size_t)NTOT * 7 + b * 2 + 0] = r0;
            ((float*)outbase)[(size_t)NTOT * 7 + b * 2 + 1] = r1;
        }
    }
}

// ---------------------------------------------------------------------------
extern "C" void kernel_launch(void* const* d_in, const int* in_sizes, int n_in,
                              void* d_out, int out_size, void* d_ws, size_t ws_size,
                              hipStream_t stream)
{
    const void* x = d_in[0];
    char* ws = (char*)d_ws;
    const size_t N = NTOT;

    __bf16* h  = (__bf16*)ws;
    size_t off = N * 1024;
    __bf16* h1 = (__bf16*)(ws + off); off += N * 512;
    float* logit = (float*)(ws + off); off += N * 4;
    __bf16* wb = (__bf16*)(ws + off); off += 331008 * 2;
    int* flag = (int*)(ws + off); off += 16;
    float2* stats = (float2*)(ws + off); off += NAUDIO * sizeof(float2);
    float* partial = (float*)(ws + off); off += (size_t)NAUDIO * POOL_CHUNKS * 128 * 4;
    __bf16* xb = (__bf16*)(ws + off); off += N * 512 * sizeof(__bf16);  // f32-path A
    __bf16* g2 = h;                        // aliases dead h
    float* emb = (float*)(ws + N * 512);   // aliases dead h (2nd half)

    const int O_W1 = 0,      O_W2 = 262144, O_as1 = 327680, O_ad1 = 328192;
    const int O_b1 = 328704, O_as2 = 328960, O_ad2 = 329216, O_b2 = 329472;
    const int O_Wt = 329600, O_bt = 329728, O_Wa = 329736, O_ba = 329992;
    const int O_Wn = 330000, O_bn = 330896;

    W14 w;
    const void* srcs[14] = { d_in[4], d_in[8], d_in[5], d_in[6], d_in[7],
                             d_in[9], d_in[10], d_in[11], d_in[12], d_in[13],
                             d_in[14], d_in[15], d_in[16], d_in[17] };
    const int ns[14]   = { 262144, 65536, 512, 512, 256, 256, 256, 128,
                           128, 1, 256, 2, 896, 7 };
    const int offs[14] = { O_W1, O_W2, O_as1, O_ad1, O_b1, O_as2, O_ad2, O_b2,
                           O_Wt, O_bt, O_Wa, O_ba, O_Wn, O_bn };
    for (int i = 0; i < 14; i++) { w.s[i] = srcs[i]; w.n[i] = ns[i]; w.off[i] = offs[i]; }

    const int nwb = NTOT / 4;

    // allow 128 KiB dynamic LDS for the 8-phase GEMMs
    {
        auto* k1 = gemm8p<true>;
        auto* k2 = gemm8p<false>;
        hipFuncSetAttribute(reinterpret_cast<const void*>(k1),
                            hipFuncAttributeMaxDynamicSharedMemorySize, 131072);
        hipFuncSetAttribute(reinterpret_cast<const void*>(k2),
                            hipFuncAttributeMaxDynamicSharedMemorySize, 131072);
    }

    detect_dtype<<<1, 256, 0, stream>>>((const unsigned*)x, flag);
    convert_weights<<<512, 256, 0, stream>>>(w, flag, wb);
    convert_x<<<2048, 256, 0, stream>>>((const float4*)x, xb, flag);

    // 1) h = x @ W1^T   (A = x if bf16 else converted xb)
    gemm8p<true><<<dim3((NTOT / 256) * 2), dim3(512), 131072, stream>>>(
        x, xb, wb + O_W1, h, NTOT, 512, 512, 2, flag);
    // 2) fused GAT layer 1: edge softmax + aggregate + relu -> h1
    agg_fused<256, true, false><<<nwb, 256, 0, stream>>>(
        h, wb + O_as1, wb + O_ad1, wb + O_b1, h1,
        nullptr, nullptr, nullptr, nullptr, nullptr, nullptr, flag);
    // 3) g2 = h1 @ W2^T
    gemm8p<false><<<dim3(NTOT / 256), dim3(512), 131072, stream>>>(
        h1, nullptr, wb + O_W2, g2, NTOT, 256, 256, 1, flag);
    // 4) fused GAT layer 2 + node head: emb (f32) + node_pred + logit
    agg_fused<128, false, true><<<nwb, 256, 0, stream>>>(
        g2, wb + O_as2, wb + O_ad2, wb + O_b2, emb,
        wb + O_Wn, wb + O_bn, wb + O_Wt, wb + O_bt, d_out, logit, flag);
    // 5) per-audio softmax pool + audio head
    audio_stats<<<NAUDIO, 256, 0, stream>>>(logit, stats);
    audio_partial<<<NAUDIO * POOL_CHUNKS, 256, 0, stream>>>(emb, logit, stats, partial);
    audio_final<<<NAUDIO, 64, 0, stream>>>(partial, wb + O_Wa, wb + O_ba, d_out, flag);
}

// Round 2
// 676.386 us; speedup vs baseline: 1.0456x; 1.0456x over previous
//
#include <hip/hip_runtime.h>
#include <hip/hip_bf16.h>

typedef __bf16 bf16x8 __attribute__((ext_vector_type(8)));
typedef float f32x4 __attribute__((ext_vector_type(4)));

#define NTOT 131072
#define NODES_PER_AUDIO 2048
#define NAUDIO 64
#define POOL_CHUNKS 16
#define CHUNK_NODES 128

// weight-buffer element offsets
#define O_W1 0
#define O_W2 262144
#define O_as1 327680
#define O_ad1 328192
#define O_b1 328704
#define O_as2 328960
#define O_ad2 329216
#define O_b2 329472
#define O_Wt 329600
#define O_bt 329728
#define O_Wa 329736
#define O_ba 329992
#define O_Wn 330000
#define O_bn 330896

#define SBAR __builtin_amdgcn_sched_barrier(0)
#define AS1 __attribute__((address_space(1)))
#define AS3 __attribute__((address_space(3)))
#define GLL(SRC, DST) __builtin_amdgcn_global_load_lds( \
    (const AS1 void*)(SRC), (AS3 void*)(DST), 16, 0, 0)

__device__ __forceinline__ float lrelu(float x) { return x > 0.f ? x : 0.2f * x; }

// ---------------------------------------------------------------------------
// dtype detection (flag=1 -> bf16 inputs, flag=0 -> f32)
// ---------------------------------------------------------------------------
__global__ __launch_bounds__(256)
void detect_dtype(const unsigned* __restrict__ x, int* __restrict__ flag)
{
    const int tid = threadIdx.x;
    int cnt = 0;
    for (int i = tid; i < 4096; i += 256) {
        unsigned e = (x[i] >> 7) & 0xFF;
        cnt += (e >= 100 && e <= 145) ? 1 : 0;
    }
    __shared__ int red[256];
    red[tid] = cnt; __syncthreads();
    for (int s = 128; s > 0; s >>= 1) {
        if (tid < s) red[tid] += red[tid + s];
        __syncthreads();
    }
    if (tid == 0) *flag = (red[0] > 3000) ? 1 : 0;
}

struct W14 { const void* s[14]; int n[14]; int off[14]; };

__global__ __launch_bounds__(256)
void convert_weights(W14 w, const int* __restrict__ flag, __bf16* __restrict__ wb)
{
    const int f = *flag;
    const int stride = gridDim.x * 256;
    for (int t = 0; t < 14; t++) {
        const void* src = w.s[t];
        __bf16* d = wb + w.off[t];
        for (int i = blockIdx.x * 256 + threadIdx.x; i < w.n[t]; i += stride)
            d[i] = f ? ((const __bf16*)src)[i] : (__bf16)((const float*)src)[i];
    }
}

__global__ __launch_bounds__(256)
void convert_x(const float4* __restrict__ xf, __bf16* __restrict__ xb,
               const int* __restrict__ flag)
{
    if (*flag) return;
    const unsigned stride = gridDim.x * 256;
    for (unsigned i = blockIdx.x * 256 + threadIdx.x; i < 16777216u; i += stride) {
        float4 v = xf[i];
        __bf16 t[4] = {(__bf16)v.x, (__bf16)v.y, (__bf16)v.z, (__bf16)v.w};
        *(int2*)&xb[(size_t)i * 4] = *(int2*)t;
    }
}

// ---------------------------------------------------------------------------
// Fused layer 1: h = x @ W1^T (128 rows x 512 cols per block, all cols),
// then in-block GAT edge-softmax + aggregation + head-mean + relu -> h1.
// Streaming GEMM: BK=32, dbuf LDS (A 2x8K + W 2x32K = 80 KB), counted
// vmcnt(5), raw barriers, T2 swizzle via inverse-swizzled global source.
// Post: acc -> hb[128][512] (bf16, reuses staging LDS), dots, alpha, agg.
// Boundary row r0 handled by fix1 via side buffers (h rows 0/127 + dots).
// ---------------------------------------------------------------------------
__global__ __launch_bounds__(512, 2)
void fused1(const void* __restrict__ Araw, const __bf16* __restrict__ Aconv,
            const __bf16* __restrict__ wb, __bf16* __restrict__ h1,
            float* __restrict__ side_al, __bf16* __restrict__ side_h,
            const int* __restrict__ flagp)
{
    extern __shared__ __align__(16) char smem[];
    __bf16* As  = (__bf16*)smem;                 // stage A [2][128][32]
    __bf16* Bs  = (__bf16*)(smem + 16384);       // stage W [2][512][32]
    __bf16* hb  = (__bf16*)smem;                 // post: h [128][512]
    float*  al  = (float*)(smem + 131072);       // [128][4] = s0,s1,d0,d1
    float*  alp = (float*)(smem + 133120);       // [128][4] = as0,ap0,as1,ap1
    __bf16* asd = (__bf16*)(smem + 135168);      // as1[512] | ad1[512]
    __bf16* b1s = (__bf16*)(smem + 137216);      // [256]

    const int tid  = threadIdx.x;
    const int b    = blockIdx.x;
    const int r0   = b * 128;
    const int wave = tid >> 6, lane = tid & 63;
    const int lr   = lane & 15, lq = lane >> 4;
    const int frs  = (lq ^ (lr & 3)) * 8;

    asd[tid]       = wb[O_as1 + tid];
    asd[512 + tid] = wb[O_ad1 + tid];
    if (tid < 256) b1s[tid] = wb[O_b1 + tid];

    const __bf16* A = (const __bf16*)Araw;
    if (!*flagp) A = Aconv;
    const __bf16* Wp = wb + O_W1;

    const int arow = tid >> 2, aslot = tid & 3;
    const size_t aoff  = (size_t)(r0 + arow) * 512 + ((aslot ^ (arow & 3)) * 8);
    const size_t boff0 = (size_t)arow * 512 + ((aslot ^ (arow & 3)) * 8);
    const int ldst = tid * 8;

    f32x4 acc[8][4] = {};

    asm volatile("s_waitcnt vmcnt(0)" ::: "memory");
    // prologue: K-step 0 into buf 0
    GLL(A + aoff, As + ldst);
    GLL(Wp + boff0,          Bs + ldst);
    GLL(Wp + boff0 + 65536,  Bs + ldst + 4096);
    GLL(Wp + boff0 + 131072, Bs + ldst + 8192);
    GLL(Wp + boff0 + 196608, Bs + ldst + 12288);

    #pragma unroll 2
    for (int s = 0; s < 16; ++s) {
        const int p = s & 1;
        if (s < 15) {
            const int ko = (s + 1) * 32;
            const int q = p ^ 1;
            GLL(A + aoff + ko, As + q * 4096 + ldst);
            GLL(Wp + boff0 + ko,          Bs + q * 16384 + ldst);
            GLL(Wp + boff0 + 65536 + ko,  Bs + q * 16384 + ldst + 4096);
            GLL(Wp + boff0 + 131072 + ko, Bs + q * 16384 + ldst + 8192);
            GLL(Wp + boff0 + 196608 + ko, Bs + q * 16384 + ldst + 12288);
            asm volatile("s_waitcnt vmcnt(5)");
        } else {
            asm volatile("s_waitcnt vmcnt(0)");
        }
        SBAR; __builtin_amdgcn_s_barrier(); SBAR;

        bf16x8 av[8], bv[4];
        #pragma unroll
        for (int i = 0; i < 8; i++)
            av[i] = *(const bf16x8*)&As[p * 4096 + (i * 16 + lr) * 32 + frs];
        #pragma unroll
        for (int j = 0; j < 4; j++)
            bv[j] = *(const bf16x8*)&Bs[p * 16384 + (wave * 64 + j * 16 + lr) * 32 + frs];
        asm volatile("s_waitcnt lgkmcnt(0)"); SBAR;
        #pragma unroll
        for (int i = 0; i < 8; i++)
            #pragma unroll
            for (int j = 0; j < 4; j++)
                acc[i][j] = __builtin_amdgcn_mfma_f32_16x16x32_bf16(
                    av[i], bv[j], acc[i][j], 0, 0, 0);
        SBAR; __builtin_amdgcn_s_barrier(); SBAR;
    }

    // acc -> hb (C/D mapping: col=lr, row=lq*4+r within 16x16 frag)
    #pragma unroll
    for (int i = 0; i < 8; i++)
        #pragma unroll
        for (int j = 0; j < 4; j++) {
            const int col = wave * 64 + j * 16 + lr;
            #pragma unroll
            for (int r = 0; r < 4; r++)
                hb[(i * 16 + lq * 4 + r) * 512 + col] = (__bf16)acc[i][j][r];
        }
    __syncthreads();

    // attention dots: al_s/al_d per row per head (rotated chunks vs banks)
    {
        const int row = tid >> 2, q = tid & 3;
        float s0 = 0.f, s1 = 0.f, d0 = 0.f, d1 = 0.f;
        #pragma unroll
        for (int c8 = 0; c8 < 8; ++c8) {
            const int cc = q * 64 + ((c8 + row) & 7) * 8;
            bf16x8 x0 = *(const bf16x8*)&hb[row * 512 + cc];
            bf16x8 x1 = *(const bf16x8*)&hb[row * 512 + 256 + cc];
            bf16x8 a0 = *(const bf16x8*)&asd[cc];
            bf16x8 a1 = *(const bf16x8*)&asd[256 + cc];
            bf16x8 e0 = *(const bf16x8*)&asd[512 + cc];
            bf16x8 e1 = *(const bf16x8*)&asd[768 + cc];
            #pragma unroll
            for (int j = 0; j < 8; j++) {
                float v0 = (float)x0[j], v1 = (float)x1[j];
                s0 += v0 * (float)a0[j]; d0 += v0 * (float)e0[j];
                s1 += v1 * (float)a1[j]; d1 += v1 * (float)e1[j];
            }
        }
        s0 += __shfl_xor(s0, 1, 64); s0 += __shfl_xor(s0, 2, 64);
        s1 += __shfl_xor(s1, 1, 64); s1 += __shfl_xor(s1, 2, 64);
        d0 += __shfl_xor(d0, 1, 64); d0 += __shfl_xor(d0, 2, 64);
        d1 += __shfl_xor(d1, 1, 64); d1 += __shfl_xor(d1, 2, 64);
        if (q == 0) {
            al[row * 4 + 0] = s0; al[row * 4 + 1] = s1;
            al[row * 4 + 2] = d0; al[row * 4 + 3] = d1;
        }
    }
    if (tid < 64) {  // save h rows 0 and 127 for boundary fixup
        *(int4*)&side_h[(size_t)b * 1024 + tid * 8]       = *(const int4*)&hb[tid * 8];
        *(int4*)&side_h[(size_t)b * 1024 + 512 + tid * 8] = *(const int4*)&hb[127 * 512 + tid * 8];
    }
    __syncthreads();

    // alpha for interior rows (interior rows always have a prev edge:
    // audio boundaries n%2048==0 land exactly on block-first rows)
    if (tid >= 1 && tid < 128) {
        const int n = tid;
        float4 a  = *(const float4*)&al[n * 4];
        float4 ap = *(const float4*)&al[(n - 1) * 4];
        float es0 = lrelu(a.x + a.z), ep0 = lrelu(ap.x + a.z);
        float m0 = fmaxf(es0, ep0);
        float w0 = __expf(es0 - m0), v0 = __expf(ep0 - m0), i0 = 1.f / (w0 + v0);
        float es1 = lrelu(a.y + a.w), ep1 = lrelu(ap.y + a.w);
        float m1 = fmaxf(es1, ep1);
        float w1 = __expf(es1 - m1), v1 = __expf(ep1 - m1), i1 = 1.f / (w1 + v1);
        *(float4*)&alp[n * 4] = make_float4(w0 * i0, v0 * i0, w1 * i1, v1 * i1);
    }
    if (tid == 0) {
        *(float4*)&side_al[(size_t)b * 8]     = *(const float4*)&al[0];
        *(float4*)&side_al[(size_t)b * 8 + 4] = *(const float4*)&al[127 * 4];
    }
    __syncthreads();

    // aggregate + head-mean + relu -> h1 for rows 1..127
    if (tid < 508) {
        const int n = 1 + (tid >> 2), q = tid & 3;
        const float4 av4 = *(const float4*)&alp[n * 4];
        #pragma unroll
        for (int c8 = 0; c8 < 8; ++c8) {
            const int cc = q * 64 + ((c8 + n) & 7) * 8;
            bf16x8 x00 = *(const bf16x8*)&hb[n * 512 + cc];
            bf16x8 x0p = *(const bf16x8*)&hb[(n - 1) * 512 + cc];
            bf16x8 x10 = *(const bf16x8*)&hb[n * 512 + 256 + cc];
            bf16x8 x1p = *(const bf16x8*)&hb[(n - 1) * 512 + 256 + cc];
            bf16x8 bb  = *(const bf16x8*)&b1s[cc];
            __bf16 o[8];
            #pragma unroll
            for (int j = 0; j < 8; j++) {
                float v = 0.5f * (av4.x * (float)x00[j] + av4.y * (float)x0p[j]
                                + av4.z * (float)x10[j] + av4.w * (float)x1p[j])
                        + (float)bb[j];
                o[j] = (__bf16)fmaxf(v, 0.f);
            }
            *(int4*)&h1[(size_t)(r0 + n) * 256 + cc] = *(const int4*)o;
        }
    }
}

// fixup: h1 row r0 of every block (needs prev block's last h row)
__global__ __launch_bounds__(256)
void fix1(const float* __restrict__ side_al, const __bf16* __restrict__ side_h,
          const __bf16* __restrict__ wb, __bf16* __restrict__ h1)
{
    const int node = blockIdx.x * 4 + (threadIdx.x >> 6);
    const int lane = threadIdx.x & 63;
    const bool hp = (node & 15) != 0;   // n = node*128; n%2048==0 <=> node%16==0
    const int pv = hp ? node - 1 : node;
    const float* alf   = side_al + (size_t)node * 8;
    const float* aprev = side_al + (size_t)pv * 8 + 4;
    float as0 = 1.f, ap0 = 0.f, as1h = 1.f, ap1 = 0.f;
    if (hp) {
        float es0 = lrelu(alf[0] + alf[2]), ep0 = lrelu(aprev[0] + alf[2]);
        float m0 = fmaxf(es0, ep0);
        float w0 = __expf(es0 - m0), v0 = __expf(ep0 - m0), i0 = 1.f / (w0 + v0);
        as0 = w0 * i0; ap0 = v0 * i0;
        float es1 = lrelu(alf[1] + alf[3]), ep1 = lrelu(aprev[1] + alf[3]);
        float m1 = fmaxf(es1, ep1);
        float w1 = __expf(es1 - m1), v1 = __expf(ep1 - m1), i1 = 1.f / (w1 + v1);
        as1h = w1 * i1; ap1 = v1 * i1;
    }
    const __bf16* hf = side_h + (size_t)node * 1024;
    const __bf16* hl = side_h + (size_t)pv * 1024 + 512;
    const int c4 = lane * 4;
    __bf16 o[4];
    #pragma unroll
    for (int r = 0; r < 4; r++) {
        const int c = c4 + r;
        float v = 0.5f * (as0 * (float)hf[c] + ap0 * (float)hl[c]
                        + as1h * (float)hf[256 + c] + ap1 * (float)hl[256 + c])
                + (float)wb[O_b1 + c];
        o[r] = (__bf16)fmaxf(v, 0.f);
    }
    *(int2*)&h1[(size_t)node * 128 * 256 + c4] = *(const int2*)o;
}

// ---------------------------------------------------------------------------
// Fused layer 2: g2 = h1 @ W2^T (128 rows x 256 cols/block), in-block GAT
// agg (no relu) -> emb (f32) + node head (softmax7 -> node_pred) + logit.
// ---------------------------------------------------------------------------
__global__ __launch_bounds__(512, 4)
void fused2(const __bf16* __restrict__ h1, const __bf16* __restrict__ wb,
            float* __restrict__ emb, float* __restrict__ side_al2,
            __bf16* __restrict__ side_h2, void* __restrict__ node_pred,
            float* __restrict__ logit, const int* __restrict__ flagp)
{
    extern __shared__ __align__(16) char smem[];
    __bf16* As  = (__bf16*)smem;                 // [2][128][32]
    __bf16* Bs  = (__bf16*)(smem + 16384);       // [2][256][32]
    __bf16* hb  = (__bf16*)smem;                 // post [128][256]
    float*  al  = (float*)(smem + 65536);
    float*  alp = (float*)(smem + 67584);
    __bf16* we  = (__bf16*)(smem + 69632);       // as2[256] | ad2[256]
    __bf16* b2s = (__bf16*)(smem + 70656);       // [128]
    __bf16* wns = (__bf16*)(smem + 70912);       // Wn[896] | Wt[128]

    const int tid  = threadIdx.x;
    const int b    = blockIdx.x;
    const int r0   = b * 128;
    const int wave = tid >> 6, lane = tid & 63;
    const int lr   = lane & 15, lq = lane >> 4;
    const int frs  = (lq ^ (lr & 3)) * 8;

    if (tid < 256) { we[tid] = wb[O_as2 + tid]; we[256 + tid] = wb[O_ad2 + tid]; }
    if (tid < 128) b2s[tid] = wb[O_b2 + tid];
    for (int i = tid; i < 1024; i += 512)
        wns[i] = (i < 896) ? wb[O_Wn + i] : wb[O_Wt + (i - 896)];

    const int arow = tid >> 2, aslot = tid & 3;
    const size_t aoff  = (size_t)(r0 + arow) * 256 + ((aslot ^ (arow & 3)) * 8);
    const size_t boff0 = (size_t)arow * 256 + ((aslot ^ (arow & 3)) * 8);
    const int ldst = tid * 8;
    const __bf16* Wp = wb + O_W2;

    f32x4 acc[8][2] = {};

    asm volatile("s_waitcnt vmcnt(0)" ::: "memory");
    GLL(h1 + aoff, As + ldst);
    GLL(Wp + boff0,         Bs + ldst);
    GLL(Wp + boff0 + 32768, Bs + ldst + 4096);

    #pragma unroll 2
    for (int s = 0; s < 8; ++s) {
        const int p = s & 1;
        if (s < 7) {
            const int ko = (s + 1) * 32;
            const int q = p ^ 1;
            GLL(h1 + aoff + ko, As + q * 4096 + ldst);
            GLL(Wp + boff0 + ko,         Bs + q * 8192 + ldst);
            GLL(Wp + boff0 + 32768 + ko, Bs + q * 8192 + ldst + 4096);
            asm volatile("s_waitcnt vmcnt(3)");
        } else {
            asm volatile("s_waitcnt vmcnt(0)");
        }
        SBAR; __builtin_amdgcn_s_barrier(); SBAR;

        bf16x8 bv[2];
        #pragma unroll
        for (int j = 0; j < 2; j++)
            bv[j] = *(const bf16x8*)&Bs[p * 8192 + (wave * 32 + j * 16 + lr) * 32 + frs];
        #pragma unroll
        for (int h = 0; h < 2; h++) {
            bf16x8 av[4];
            #pragma unroll
            for (int i = 0; i < 4; i++)
                av[i] = *(const bf16x8*)&As[p * 4096 + ((h * 4 + i) * 16 + lr) * 32 + frs];
            asm volatile("s_waitcnt lgkmcnt(0)"); SBAR;
            #pragma unroll
            for (int i = 0; i < 4; i++)
                #pragma unroll
                for (int j = 0; j < 2; j++)
                    acc[h * 4 + i][j] = __builtin_amdgcn_mfma_f32_16x16x32_bf16(
                        av[i], bv[j], acc[h * 4 + i][j], 0, 0, 0);
        }
        SBAR; __builtin_amdgcn_s_barrier(); SBAR;
    }

    #pragma unroll
    for (int i = 0; i < 8; i++)
        #pragma unroll
        for (int j = 0; j < 2; j++) {
            const int col = wave * 32 + j * 16 + lr;
            #pragma unroll
            for (int r = 0; r < 4; r++)
                hb[(i * 16 + lq * 4 + r) * 256 + col] = (__bf16)acc[i][j][r];
        }
    __syncthreads();

    {
        const int row = tid >> 2, q = tid & 3;
        float s0 = 0.f, s1 = 0.f, d0 = 0.f, d1 = 0.f;
        #pragma unroll
        for (int c4 = 0; c4 < 4; ++c4) {
            const int cc = q * 32 + ((c4 + row) & 3) * 8;
            bf16x8 x0 = *(const bf16x8*)&hb[row * 256 + cc];
            bf16x8 x1 = *(const bf16x8*)&hb[row * 256 + 128 + cc];
            bf16x8 a0 = *(const bf16x8*)&we[cc];
            bf16x8 a1 = *(const bf16x8*)&we[128 + cc];
            bf16x8 e0 = *(const bf16x8*)&we[256 + cc];
            bf16x8 e1 = *(const bf16x8*)&we[384 + cc];
            #pragma unroll
            for (int j = 0; j < 8; j++) {
                float v0 = (float)x0[j], v1 = (float)x1[j];
                s0 += v0 * (float)a0[j]; d0 += v0 * (float)e0[j];
                s1 += v1 * (float)a1[j]; d1 += v1 * (float)e1[j];
            }
        }
        s0 += __shfl_xor(s0, 1, 64); s0 += __shfl_xor(s0, 2, 64);
        s1 += __shfl_xor(s1, 1, 64); s1 += __shfl_xor(s1, 2, 64);
        d0 += __shfl_xor(d0, 1, 64); d0 += __shfl_xor(d0, 2, 64);
        d1 += __shfl_xor(d1, 1, 64); d1 += __shfl_xor(d1, 2, 64);
        if (q == 0) {
            al[row * 4 + 0] = s0; al[row * 4 + 1] = s1;
            al[row * 4 + 2] = d0; al[row * 4 + 3] = d1;
        }
    }
    if (tid < 32) {
        *(int4*)&side_h2[(size_t)b * 512 + tid * 8] = *(const int4*)&hb[tid * 8];
    } else if (tid < 64) {
        const int t = tid - 32;
        *(int4*)&side_h2[(size_t)b * 512 + 256 + t * 8] = *(const int4*)&hb[127 * 256 + t * 8];
    }
    __syncthreads();

    if (tid >= 1 && tid < 128) {
        const int n = tid;
        float4 a  = *(const float4*)&al[n * 4];
        float4 ap = *(const float4*)&al[(n - 1) * 4];
        float es0 = lrelu(a.x + a.z), ep0 = lrelu(ap.x + a.z);
        float m0 = fmaxf(es0, ep0);
        float w0 = __expf(es0 - m0), v0 = __expf(ep0 - m0), i0 = 1.f / (w0 + v0);
        float es1 = lrelu(a.y + a.w), ep1 = lrelu(ap.y + a.w);
        float m1 = fmaxf(es1, ep1);
        float w1 = __expf(es1 - m1), v1 = __expf(ep1 - m1), i1 = 1.f / (w1 + v1);
        *(float4*)&alp[n * 4] = make_float4(w0 * i0, v0 * i0, w1 * i1, v1 * i1);
    }
    if (tid == 0) {
        *(float4*)&side_al2[(size_t)b * 8]     = *(const float4*)&al[0];
        *(float4*)&side_al2[(size_t)b * 8 + 4] = *(const float4*)&al[127 * 4];
    }
    __syncthreads();

    if (tid < 508) {
        const int n = 1 + (tid >> 2), q = tid & 3;
        const float4 av4 = *(const float4*)&alp[n * 4];
        float ak[8] = {0.f, 0.f, 0.f, 0.f, 0.f, 0.f, 0.f, 0.f};
        #pragma unroll
        for (int c4 = 0; c4 < 4; ++c4) {
            const int cc = q * 32 + ((c4 + n) & 3) * 8;
            bf16x8 x00 = *(const bf16x8*)&hb[n * 256 + cc];
            bf16x8 x0p = *(const bf16x8*)&hb[(n - 1) * 256 + cc];
            bf16x8 x10 = *(const bf16x8*)&hb[n * 256 + 128 + cc];
            bf16x8 x1p = *(const bf16x8*)&hb[(n - 1) * 256 + 128 + cc];
            bf16x8 bb  = *(const bf16x8*)&b2s[cc];
            float o[8];
            #pragma unroll
            for (int j = 0; j < 8; j++)
                o[j] = 0.5f * (av4.x * (float)x00[j] + av4.y * (float)x0p[j]
                             + av4.z * (float)x10[j] + av4.w * (float)x1p[j])
                     + (float)bb[j];
            *(float4*)&emb[(size_t)(r0 + n) * 128 + cc]     = make_float4(o[0], o[1], o[2], o[3]);
            *(float4*)&emb[(size_t)(r0 + n) * 128 + cc + 4] = make_float4(o[4], o[5], o[6], o[7]);
            #pragma unroll
            for (int k = 0; k < 7; k++) {
                float t = 0.f;
                #pragma unroll
                for (int j = 0; j < 8; j++) t += o[j] * (float)wns[k * 128 + cc + j];
                ak[k] += t;
            }
            float t = 0.f;
            #pragma unroll
            for (int j = 0; j < 8; j++) t += o[j] * (float)wns[896 + cc + j];
            ak[7] += t;
        }
        #pragma unroll
        for (int k = 0; k < 8; k++) {
            ak[k] += __shfl_xor(ak[k], 1, 64);
            ak[k] += __shfl_xor(ak[k], 2, 64);
        }
        if (q == 0) {
            const size_t ng = (size_t)(r0 + n);
            float lg[7], m = -1e30f;
            #pragma unroll
            for (int k = 0; k < 7; k++) { lg[k] = ak[k] + (float)wb[O_bn + k]; m = fmaxf(m, lg[k]); }
            float s = 0.f;
            #pragma unroll
            for (int k = 0; k < 7; k++) { lg[k] = __expf(lg[k] - m); s += lg[k]; }
            float inv = 1.f / s;
            if (*flagp) {
                #pragma unroll
                for (int k = 0; k < 7; k++)
                    ((__bf16*)node_pred)[ng * 7 + k] = (__bf16)(lg[k] * inv);
            } else {
                #pragma unroll
                for (int k = 0; k < 7; k++)
                    ((float*)node_pred)[ng * 7 + k] = lg[k] * inv;
            }
            logit[ng] = ak[7] + (float)wb[O_bt];
        }
    }
}

__global__ __launch_bounds__(256)
void fix2(const float* __restrict__ side_al2, const __bf16* __restrict__ side_h2,
          const __bf16* __restrict__ wb, float* __restrict__ emb,
          void* __restrict__ node_pred, float* __restrict__ logit,
          const int* __restrict__ flagp)
{
    const int node = blockIdx.x * 4 + (threadIdx.x >> 6);
    const int lane = threadIdx.x & 63;
    const bool hp = (node & 15) != 0;
    const int pv = hp ? node - 1 : node;
    const float* alf   = side_al2 + (size_t)node * 8;
    const float* aprev = side_al2 + (size_t)pv * 8 + 4;
    float as0 = 1.f, ap0 = 0.f, as1h = 1.f, ap1 = 0.f;
    if (hp) {
        float es0 = lrelu(alf[0] + alf[2]), ep0 = lrelu(aprev[0] + alf[2]);
        float m0 = fmaxf(es0, ep0);
        float w0 = __expf(es0 - m0), v0 = __expf(ep0 - m0), i0 = 1.f / (w0 + v0);
        as0 = w0 * i0; ap0 = v0 * i0;
        float es1 = lrelu(alf[1] + alf[3]), ep1 = lrelu(aprev[1] + alf[3]);
        float m1 = fmaxf(es1, ep1);
        float w1 = __expf(es1 - m1), v1 = __expf(ep1 - m1), i1 = 1.f / (w1 + v1);
        as1h = w1 * i1; ap1 = v1 * i1;
    }
    const __bf16* gf = side_h2 + (size_t)node * 512;
    const __bf16* gl = side_h2 + (size_t)pv * 512 + 256;
    const int c2 = lane * 2;
    float o0 = 0.5f * (as0 * (float)gf[c2] + ap0 * (float)gl[c2]
                     + as1h * (float)gf[128 + c2] + ap1 * (float)gl[128 + c2])
             + (float)wb[O_b2 + c2];
    float o1 = 0.5f * (as0 * (float)gf[c2 + 1] + ap0 * (float)gl[c2 + 1]
                     + as1h * (float)gf[128 + c2 + 1] + ap1 * (float)gl[128 + c2 + 1])
             + (float)wb[O_b2 + c2 + 1];
    const size_t ng = (size_t)node * 128;
    *(float2*)&emb[ng * 128 + c2] = make_float2(o0, o1);
    float ak[8];
    #pragma unroll
    for (int k = 0; k < 7; k++)
        ak[k] = o0 * (float)wb[O_Wn + k * 128 + c2] + o1 * (float)wb[O_Wn + k * 128 + c2 + 1];
    ak[7] = o0 * (float)wb[O_Wt + c2] + o1 * (float)wb[O_Wt + c2 + 1];
    #pragma unroll
    for (int off = 1; off < 64; off <<= 1)
        #pragma unroll
        for (int k = 0; k < 8; k++) ak[k] += __shfl_xor(ak[k], off, 64);
    if (lane == 0) {
        float lg[7], m = -1e30f;
        #pragma unroll
        for (int k = 0; k < 7; k++) { lg[k] = ak[k] + (float)wb[O_bn + k]; m = fmaxf(m, lg[k]); }
        float s = 0.f;
        #pragma unroll
        for (int k = 0; k < 7; k++) { lg[k] = __expf(lg[k] - m); s += lg[k]; }
        float inv = 1.f / s;
        if (*flagp) {
            #pragma unroll
            for (int k = 0; k < 7; k++)
                ((__bf16*)node_pred)[ng * 7 + k] = (__bf16)(lg[k] * inv);
        } else {
            #pragma unroll
            for (int k = 0; k < 7; k++)
                ((float*)node_pred)[ng * 7 + k] = lg[k] * inv;
        }
        logit[ng] = ak[7] + (float)wb[O_bt];
    }
}

// ---------------------------------------------------------------------------
__global__ __launch_bounds__(256)
void audio_stats(const float* __restrict__ logit, float2* __restrict__ stats)
{
    const int b = blockIdx.x;
    const int tid = threadIdx.x;
    __shared__ float red[256];
    const float* lg = logit + b * NODES_PER_AUDIO;

    float m = -1e30f;
    for (int i = tid; i < NODES_PER_AUDIO; i += 256) m = fmaxf(m, lg[i]);
    red[tid] = m; __syncthreads();
    for (int s = 128; s > 0; s >>= 1) {
        if (tid < s) red[tid] = fmaxf(red[tid], red[tid + s]);
        __syncthreads();
    }
    m = red[0]; __syncthreads();

    float s = 0.f;
    for (int i = tid; i < NODES_PER_AUDIO; i += 256) s += __expf(lg[i] - m);
    red[tid] = s; __syncthreads();
    for (int st = 128; st > 0; st >>= 1) {
        if (tid < st) red[tid] += red[tid + st];
        __syncthreads();
    }
    if (tid == 0) stats[b] = make_float2(m, 1.f / red[0]);
}

__global__ __launch_bounds__(256)
void audio_partial(const float* __restrict__ emb, const float* __restrict__ logit,
                   const float2* __restrict__ stats, float* __restrict__ partial)
{
    const int b = blockIdx.x >> 4;
    const int chunk = blockIdx.x & 15;
    const int tid = threadIdx.x;
    const int c = tid & 127, half = tid >> 7;
    const float m = stats[b].x, inv = stats[b].y;
    const float* lg = logit + b * NODES_PER_AUDIO;
    const float* eb = emb + (size_t)b * NODES_PER_AUDIO * 128;

    __shared__ float attbuf[256];
    const int n0 = chunk * CHUNK_NODES + half * (CHUNK_NODES / 2);
    float att = 0.f;
    for (int i = n0; i < n0 + CHUNK_NODES / 2; i++) {
        float w = __expf(lg[i] - m) * inv;
        att += w * eb[(size_t)i * 128 + c];
    }
    attbuf[tid] = att; __syncthreads();
    if (tid < 128)
        partial[(size_t)(b * POOL_CHUNKS + chunk) * 128 + tid] =
            attbuf[tid] + attbuf[tid + 128];
}

__global__ __launch_bounds__(64)
void audio_final(const float* __restrict__ partial, const __bf16* __restrict__ Wa,
                 const __bf16* __restrict__ ba, void* __restrict__ outbase,
                 const int* __restrict__ flag)
{
    const int b = blockIdx.x;
    const int lane = threadIdx.x;
    const float* pb = partial + (size_t)b * POOL_CHUNKS * 128;

    float a0 = 0.f, a1 = 0.f;
    #pragma unroll
    for (int k = 0; k < POOL_CHUNKS; k++) {
        a0 += pb[k * 128 + lane * 2];
        a1 += pb[k * 128 + lane * 2 + 1];
    }
    float p0 = a0 * (float)Wa[lane * 2]       + a1 * (float)Wa[lane * 2 + 1];
    float p1 = a0 * (float)Wa[128 + lane * 2] + a1 * (float)Wa[128 + lane * 2 + 1];
    #pragma unroll
    for (int off = 1; off < 64; off <<= 1) {
        p0 += __shfl_xor(p0, off, 64);
        p1 += __shfl_xor(p1, off, 64);
    }
    if (lane == 0) {
        float r0 = p0 + (float)ba[0];
        float r1 = p1 + (float)ba[1];
        if (*flag) {
            ((__bf16*)outbase)[(size_t)NTOT * 7 + b * 2 + 0] = (__bf16)r0;
            ((__bf16*)outbase)[(size_t)NTOT * 7 + b * 2 + 1] = (__bf16)r1;
        } else {
            ((float*)outbase)[(size_t)NTOT * 7 + b * 2 + 0] = r0;
            ((float*)outbase)[(size_t)NTOT * 7 + b * 2 + 1] = r1;
        }
    }
}

// ---------------------------------------------------------------------------
extern "C" void kernel_launch(void* const* d_in, const int* in_sizes, int n_in,
                              void* d_out, int out_size, void* d_ws, size_t ws_size,
                              hipStream_t stream)
{
    const void* x = d_in[0];
    char* ws = (char*)d_ws;

    __bf16* h1       = (__bf16*)ws;                    // 67,108,864
    float*  emb      = (float*)(ws + 67108864);        // 67,108,864
    float*  logit    = (float*)(ws + 134217728);       // 524,288
    __bf16* wb       = (__bf16*)(ws + 134742016);      // 662,016
    int*    flag     = (int*)(ws + 135404032);         // 16
    float2* stats    = (float2*)(ws + 135404048);      // 512
    float*  partial  = (float*)(ws + 135404560);       // 524,288
    float*  side_al  = (float*)(ws + 135928848);       // 32,768
    __bf16* side_h   = (__bf16*)(ws + 135961616);      // 2,097,152
    float*  side_al2 = (float*)(ws + 138058768);       // 32,768
    __bf16* side_h2  = (__bf16*)(ws + 138091536);      // 1,048,576
    __bf16* xb       = (__bf16*)(ws + 139140112);      // 134,217,728

    W14 w;
    const void* srcs[14] = { d_in[4], d_in[8], d_in[5], d_in[6], d_in[7],
                             d_in[9], d_in[10], d_in[11], d_in[12], d_in[13],
                             d_in[14], d_in[15], d_in[16], d_in[17] };
    const int ns[14]   = { 262144, 65536, 512, 512, 256, 256, 256, 128,
                           128, 1, 256, 2, 896, 7 };
    const int offs[14] = { O_W1, O_W2, O_as1, O_ad1, O_b1, O_as2, O_ad2, O_b2,
                           O_Wt, O_bt, O_Wa, O_ba, O_Wn, O_bn };
    for (int i = 0; i < 14; i++) { w.s[i] = srcs[i]; w.n[i] = ns[i]; w.off[i] = offs[i]; }

    hipFuncSetAttribute(reinterpret_cast<const void*>(&fused1),
                        hipFuncAttributeMaxDynamicSharedMemorySize, 137728);
    hipFuncSetAttribute(reinterpret_cast<const void*>(&fused2),
                        hipFuncAttributeMaxDynamicSharedMemorySize, 73728);

    detect_dtype<<<1, 256, 0, stream>>>((const unsigned*)x, flag);
    convert_weights<<<512, 256, 0, stream>>>(w, flag, wb);
    convert_x<<<2048, 256, 0, stream>>>((const float4*)x, xb, flag);

    // layer 1 (GEMM + GAT agg + relu) -> h1
    fused1<<<1024, 512, 137728, stream>>>(x, xb, wb, h1, side_al, side_h, flag);
    fix1<<<256, 256, 0, stream>>>(side_al, side_h, wb, h1);
    // layer 2 (GEMM + GAT agg + node head) -> emb, node_pred, logit
    fused2<<<1024, 512, 73728, stream>>>(h1, wb, emb, side_al2, side_h2,
                                         d_out, logit, flag);
    fix2<<<256, 256, 0, stream>>>(side_al2, side_h2, wb, emb, d_out, logit, flag);
    // per-audio softmax pool + audio head
    audio_stats<<<NAUDIO, 256, 0, stream>>>(logit, stats);
    audio_partial<<<NAUDIO * POOL_CHUNKS, 256, 0, stream>>>(emb, logit, stats, partial);
    audio_final<<<NAUDIO, 64, 0, stream>>>(partial, wb + O_Wa, wb + O_ba, d_out, flag);
}